// Round 1
// baseline (1609.547 us; speedup 1.0000x reference)
//
#include <hip/hip_runtime.h>

#define D_IN 50
#define D_H 128
#define LN_EPS 1e-5f

// ---------------------------------------------------------------- CSR build
__global__ void hist_k(const int* __restrict__ dst, int* __restrict__ cnt, int e) {
    int i = blockIdx.x * blockDim.x + threadIdx.x;
    if (i < e) atomicAdd(&cnt[dst[i]], 1);
}

__global__ void scan_partial_k(const int* __restrict__ cnt, int* __restrict__ part, int n) {
    __shared__ int lds[256];
    int base = blockIdx.x * 1024;
    int t = threadIdx.x;
    int s = 0;
    for (int j = 0; j < 4; j++) {
        int idx = base + t * 4 + j;
        if (idx < n) s += cnt[idx];
    }
    lds[t] = s;
    __syncthreads();
    for (int off = 128; off > 0; off >>= 1) {
        if (t < off) lds[t] += lds[t + off];
        __syncthreads();
    }
    if (t == 0) part[blockIdx.x] = lds[0];
}

__global__ void scan_root_k(int* part, int nb) {
    if (threadIdx.x == 0 && blockIdx.x == 0) {
        int run = 0;
        for (int i = 0; i < nb; i++) { int v = part[i]; part[i] = run; run += v; }
    }
}

__global__ void scan_final_k(const int* __restrict__ cnt, const int* __restrict__ part,
                             int* __restrict__ row_ptr, int* __restrict__ pos, int n) {
    __shared__ int lds[256];
    int base = blockIdx.x * 1024;
    int t = threadIdx.x;
    int v[4];
    int s = 0;
    for (int j = 0; j < 4; j++) {
        int idx = base + t * 4 + j;
        v[j] = (idx < n) ? cnt[idx] : 0;
        s += v[j];
    }
    lds[t] = s;
    __syncthreads();
    // Hillis-Steele inclusive scan over 256 thread-sums
    for (int off = 1; off < 256; off <<= 1) {
        int xv = (t >= off) ? lds[t - off] : 0;
        __syncthreads();
        lds[t] += xv;
        __syncthreads();
    }
    int ex = (t > 0 ? lds[t - 1] : 0) + part[blockIdx.x];
    for (int j = 0; j < 4; j++) {
        int idx = base + t * 4 + j;
        if (idx < n) {
            row_ptr[idx] = ex;
            pos[idx] = ex;
            if (idx == n - 1) row_ptr[n] = ex + v[j];
            ex += v[j];
        }
    }
}

__global__ void fill_k(const int* __restrict__ src, const int* __restrict__ dst,
                       int* __restrict__ pos, int* __restrict__ col, int e) {
    int i = blockIdx.x * blockDim.x + threadIdx.x;
    if (i < e) {
        int d = dst[i];
        int p = atomicAdd(&pos[d], 1);
        col[p] = src[i];
    }
}

// ------------------------------------------------------------- aggregation
// one wave per node; mean over in-neighbors
__global__ void agg_d50_k(const float* __restrict__ feat, const int* __restrict__ rp,
                          const int* __restrict__ col, float* __restrict__ mean, int n) {
    int wid = (blockIdx.x * blockDim.x + threadIdx.x) >> 6;
    int lane = threadIdx.x & 63;
    if (wid >= n) return;
    int start = rp[wid], end = rp[wid + 1];
    float acc = 0.f;
    if (lane < D_IN) {
        int e = start;
        for (; e + 1 < end; e += 2) {
            int s0 = col[e], s1 = col[e + 1];
            acc += feat[(size_t)s0 * D_IN + lane];
            acc += feat[(size_t)s1 * D_IN + lane];
        }
        if (e < end) {
            int s0 = col[e];
            acc += feat[(size_t)s0 * D_IN + lane];
        }
    }
    int c = end - start;
    float invc = 1.f / (float)(c > 0 ? c : 1);
    if (lane < D_IN) mean[(size_t)wid * D_IN + lane] = acc * invc;
}

__global__ void agg_d128_k(const float* __restrict__ feat, const int* __restrict__ rp,
                           const int* __restrict__ col, float* __restrict__ mean, int n) {
    int wid = (blockIdx.x * blockDim.x + threadIdx.x) >> 6;
    int lane = threadIdx.x & 63;
    if (wid >= n) return;
    int start = rp[wid], end = rp[wid + 1];
    const float2* f2 = (const float2*)feat;
    float2 acc = make_float2(0.f, 0.f);
    int e = start;
    for (; e + 1 < end; e += 2) {
        int s0 = col[e], s1 = col[e + 1];
        float2 v0 = f2[(size_t)s0 * 64 + lane];
        float2 v1 = f2[(size_t)s1 * 64 + lane];
        acc.x += v0.x + v1.x;
        acc.y += v0.y + v1.y;
    }
    if (e < end) {
        int s0 = col[e];
        float2 v0 = f2[(size_t)s0 * 64 + lane];
        acc.x += v0.x;
        acc.y += v0.y;
    }
    int c = end - start;
    float invc = 1.f / (float)(c > 0 ? c : 1);
    float2 o;
    o.x = acc.x * invc;
    o.y = acc.y * invc;
    ((float2*)mean)[(size_t)wid * 64 + lane] = o;
}

// ------------------------------------------------- fused SAGE linear (GEMM)
// out[n][0:128] = A[n][:]@Wl + (DUAL? B[n][:]@Wr) + bias; optional LN sum/sumsq
#define COMP(v, c) ((c) == 0 ? (v).x : ((c) == 1 ? (v).y : ((c) == 2 ? (v).z : (v).w)))

template <int DIN, bool DUAL, bool ACC>
__global__ __launch_bounds__(256) void sage_linear_k(
    const float* A, const float* B,
    const float* __restrict__ Wl, const float* __restrict__ Wr,
    const float* __restrict__ bias,
    float* out, double* __restrict__ lnacc, int n) {
    constexpr int BK = 16;
    __shared__ alignas(16) float As[64 * BK];
    __shared__ alignas(16) float Bs[DUAL ? 64 * BK : 4];
    __shared__ float wsum[4], wsum2[4];

    const int tid = threadIdx.x;
    const int tx = tid & 31;   // col group: cols tx*4..tx*4+3
    const int ty = tid >> 5;   // 0..7: rows ty+8*j
    const int row0 = blockIdx.x * 64;

    float acc[8][4];
#pragma unroll
    for (int j = 0; j < 8; j++)
#pragma unroll
        for (int i = 0; i < 4; i++) acc[j][i] = 0.f;

    for (int k0 = 0; k0 < DIN; k0 += BK) {
        __syncthreads();
        // stage 64 x BK tiles of A (and B)
#pragma unroll
        for (int u = 0; u < 4; u++) {
            int l = tid * 4 + u;
            int r = l >> 4;
            int kc = l & 15;
            int gr = row0 + r;
            int gk = k0 + kc;
            float va = 0.f, vb = 0.f;
            if (gr < n && gk < DIN) {
                va = A[(size_t)gr * DIN + gk];
                if (DUAL) vb = B[(size_t)gr * DIN + gk];
            }
            As[l] = va;
            if (DUAL) Bs[l] = vb;
        }
        __syncthreads();
#pragma unroll
        for (int kk = 0; kk < BK; kk += 4) {
            float4 wl[4], wr[4];
#pragma unroll
            for (int i = 0; i < 4; i++) {
                int k = k0 + kk + i;
                if (k < DIN) {
                    wl[i] = *(const float4*)(Wl + (size_t)k * 128 + tx * 4);
                    if (DUAL) wr[i] = *(const float4*)(Wr + (size_t)k * 128 + tx * 4);
                } else {
                    wl[i] = make_float4(0.f, 0.f, 0.f, 0.f);
                    if (DUAL) wr[i] = make_float4(0.f, 0.f, 0.f, 0.f);
                }
            }
#pragma unroll
            for (int j = 0; j < 8; j++) {
                const int rl = ty + 8 * j;
                const float4 av = *(const float4*)(&As[rl * BK + kk]);
#pragma unroll
                for (int i = 0; i < 4; i++) {
                    float ai = COMP(av, i);
#pragma unroll
                    for (int c = 0; c < 4; c++)
                        acc[j][c] = fmaf(ai, COMP(wl[i], c), acc[j][c]);
                }
                if (DUAL) {
                    const float4 bv = *(const float4*)(&Bs[rl * BK + kk]);
#pragma unroll
                    for (int i = 0; i < 4; i++) {
                        float bi = COMP(bv, i);
#pragma unroll
                        for (int c = 0; c < 4; c++)
                            acc[j][c] = fmaf(bi, COMP(wr[i], c), acc[j][c]);
                    }
                }
            }
        }
    }

    float4 b4 = bias ? *(const float4*)(bias + tx * 4) : make_float4(0.f, 0.f, 0.f, 0.f);
    float lsum = 0.f, lsum2 = 0.f;
#pragma unroll
    for (int j = 0; j < 8; j++) {
        int gr = row0 + ty + 8 * j;
        if (gr < n) {
            float4 o;
            o.x = acc[j][0] + b4.x;
            o.y = acc[j][1] + b4.y;
            o.z = acc[j][2] + b4.z;
            o.w = acc[j][3] + b4.w;
            *(float4*)(out + (size_t)gr * 128 + tx * 4) = o;
            if (ACC) {
                lsum += o.x + o.y + o.z + o.w;
                lsum2 += o.x * o.x + o.y * o.y + o.z * o.z + o.w * o.w;
            }
        }
    }
    if (ACC) {
        for (int off = 32; off > 0; off >>= 1) {
            lsum += __shfl_down(lsum, off);
            lsum2 += __shfl_down(lsum2, off);
        }
        int wave = tid >> 6, lane = tid & 63;
        if (lane == 0) { wsum[wave] = lsum; wsum2[wave] = lsum2; }
        __syncthreads();
        if (tid == 0) {
            float s = 0.f, s2 = 0.f;
            for (int w = 0; w < 4; w++) { s += wsum[w]; s2 += wsum2[w]; }
            atomicAdd(lnacc, (double)s);
            atomicAdd(lnacc + 1, (double)s2);
        }
    }
}

// --------------------------------------------- LN (graph mode) + PReLU (+skip)
// MODE 1: out0 = h1 = prelu(ln(pre)); out1 = h1 + s          (t2, in-place over pre ok)
// MODE 2: out0 = t3 = h1_in + prelu(ln(pre)) + s
// MODE 3: out0 = prelu(ln(pre))
template <int MODE>
__global__ void ln_prelu_k(const float* __restrict__ pre, const float* __restrict__ h1in,
                           const float* __restrict__ s,
                           const float* __restrict__ lnw, const float* __restrict__ lnb,
                           const float* __restrict__ a_ptr, const double* __restrict__ acc,
                           float* __restrict__ out0, float* __restrict__ out1, int total) {
    int i = blockIdx.x * blockDim.x + threadIdx.x;  // float4 index
    if (i * 4 >= total) return;
    double cinv = 1.0 / (double)total;
    double m = acc[0] * cinv;
    double var = acc[1] * cinv - m * m;
    float stdv = (float)sqrt(var > 0.0 ? var : 0.0);
    float scale = 1.0f / (stdv + LN_EPS);
    float mf = (float)m;
    float a = a_ptr[0];
    int c4 = i & 31;
    float4 w = ((const float4*)lnw)[c4];
    float4 b = ((const float4*)lnb)[c4];
    float4 p = ((const float4*)pre)[i];
    float4 h;
    h.x = (p.x - mf) * scale * w.x + b.x;
    h.y = (p.y - mf) * scale * w.y + b.y;
    h.z = (p.z - mf) * scale * w.z + b.z;
    h.w = (p.w - mf) * scale * w.w + b.w;
    h.x = h.x >= 0.f ? h.x : a * h.x;
    h.y = h.y >= 0.f ? h.y : a * h.y;
    h.z = h.z >= 0.f ? h.z : a * h.z;
    h.w = h.w >= 0.f ? h.w : a * h.w;
    if (MODE == 1) {
        ((float4*)out0)[i] = h;
        float4 sv = ((const float4*)s)[i];
        float4 t;
        t.x = h.x + sv.x; t.y = h.y + sv.y; t.z = h.z + sv.z; t.w = h.w + sv.w;
        ((float4*)out1)[i] = t;
    } else if (MODE == 2) {
        float4 hv = ((const float4*)h1in)[i];
        float4 sv = ((const float4*)s)[i];
        float4 t;
        t.x = hv.x + h.x + sv.x; t.y = hv.y + h.y + sv.y;
        t.z = hv.z + h.z + sv.z; t.w = hv.w + h.w + sv.w;
        ((float4*)out0)[i] = t;
    } else {
        ((float4*)out0)[i] = h;
    }
}

// ------------------------------------------------------------------ launch
extern "C" void kernel_launch(void* const* d_in, const int* in_sizes, int n_in,
                              void* d_out, int out_size, void* d_ws, size_t ws_size,
                              hipStream_t stream) {
    const float* x    = (const float*)d_in[0];
    const int*   esrc = (const int*)d_in[1];
    const int*   edst = (const int*)d_in[2];
    const float* Wl1  = (const float*)d_in[3];
    const float* Wr1  = (const float*)d_in[4];
    const float* b1   = (const float*)d_in[5];
    const float* Wl2  = (const float*)d_in[6];
    const float* Wr2  = (const float*)d_in[7];
    const float* b2   = (const float*)d_in[8];
    const float* Wl3  = (const float*)d_in[9];
    const float* Wr3  = (const float*)d_in[10];
    const float* b3   = (const float*)d_in[11];
    const float* Ws1  = (const float*)d_in[12];
    const float* Ws2  = (const float*)d_in[13];
    const float* lnw1 = (const float*)d_in[14];
    const float* lnb1 = (const float*)d_in[15];
    const float* lnw2 = (const float*)d_in[16];
    const float* lnb2 = (const float*)d_in[17];
    const float* lnw3 = (const float*)d_in[18];
    const float* lnb3 = (const float*)d_in[19];
    const float* a1   = (const float*)d_in[20];
    const float* a2   = (const float*)d_in[21];
    const float* a3   = (const float*)d_in[22];

    const int N = in_sizes[0] / D_IN;
    const int E = in_sizes[1];

    char* ws = (char*)d_ws;
    size_t off = 0;
    auto alloc = [&](size_t bytes) -> void* {
        void* p = ws + off;
        off += (bytes + 255) & ~(size_t)255;
        return p;
    };
    float* A  = (float*)alloc((size_t)N * 128 * 4);  // mean / pre (in-place)
    float* Bb = (float*)alloc((size_t)N * 128 * 4);  // h1
    float* C  = (float*)alloc((size_t)N * 128 * 4);  // s1 then s2
    float* D  = (float*)alloc((size_t)N * 128 * 4);  // h1_pre -> t2 -> t3
    int* cnt  = (int*)alloc((size_t)N * 4);
    int* rp   = (int*)alloc((size_t)(N + 1) * 4);
    int* pos  = (int*)alloc((size_t)N * 4);
    int* col  = (int*)alloc((size_t)E * 4);
    int* part = (int*)alloc(512);
    double* lnacc = (double*)alloc(6 * 8);

    hipMemsetAsync(cnt, 0, (size_t)N * 4, stream);
    hipMemsetAsync(lnacc, 0, 48, stream);

    const int CH = 1024;
    const int NBS = (N + CH - 1) / CH;
    hist_k<<<(E + 255) / 256, 256, 0, stream>>>(edst, cnt, E);
    scan_partial_k<<<NBS, 256, 0, stream>>>(cnt, part, N);
    scan_root_k<<<1, 64, 0, stream>>>(part, NBS);
    scan_final_k<<<NBS, 256, 0, stream>>>(cnt, part, rp, pos, N);
    fill_k<<<(E + 255) / 256, 256, 0, stream>>>(esrc, edst, pos, col, E);

    const int aggBlocks = ((N * 64) + 255) / 256;
    const int gemmBlocks = (N + 63) / 64;
    const int lnBlocks = (N * 128 / 4 + 255) / 256;
    const int total = N * 128;

    // ---- layer 1
    agg_d50_k<<<aggBlocks, 256, 0, stream>>>(x, rp, col, A, N);
    sage_linear_k<50, true, true><<<gemmBlocks, 256, 0, stream>>>(
        A, x, Wl1, Wr1, b1, D, lnacc + 0, N);                       // D = h1_pre
    sage_linear_k<50, false, false><<<gemmBlocks, 256, 0, stream>>>(
        x, nullptr, Ws1, nullptr, nullptr, C, nullptr, N);          // C = x@Ws1
    ln_prelu_k<1><<<lnBlocks, 256, 0, stream>>>(
        D, nullptr, C, lnw1, lnb1, a1, lnacc + 0, Bb, D, total);    // Bb = h1, D = t2

    // ---- layer 2
    agg_d128_k<<<aggBlocks, 256, 0, stream>>>(D, rp, col, A, N);    // A = mean2
    sage_linear_k<128, true, true><<<gemmBlocks, 256, 0, stream>>>(
        A, D, Wl2, Wr2, b2, A, lnacc + 2, N);                       // A = h2_pre (in-place)
    sage_linear_k<50, false, false><<<gemmBlocks, 256, 0, stream>>>(
        x, nullptr, Ws2, nullptr, nullptr, C, nullptr, N);          // C = x@Ws2
    ln_prelu_k<2><<<lnBlocks, 256, 0, stream>>>(
        A, Bb, C, lnw2, lnb2, a2, lnacc + 2, D, nullptr, total);    // D = t3

    // ---- layer 3
    agg_d128_k<<<aggBlocks, 256, 0, stream>>>(D, rp, col, A, N);    // A = mean3
    sage_linear_k<128, true, true><<<gemmBlocks, 256, 0, stream>>>(
        A, D, Wl3, Wr3, b3, A, lnacc + 4, N);                       // A = ret_pre (in-place)
    ln_prelu_k<3><<<lnBlocks, 256, 0, stream>>>(
        A, nullptr, nullptr, lnw3, lnb3, a3, lnacc + 4, (float*)d_out, nullptr, total);
}

// Round 2
// 1246.722 us; speedup vs baseline: 1.2910x; 1.2910x over previous
//
#include <hip/hip_runtime.h>

#define D_IN 50
#define LN_EPS 1e-5f

typedef __bf16 bf16_t;
typedef bf16_t bf16x8 __attribute__((ext_vector_type(8)));
typedef bf16_t bf16x4 __attribute__((ext_vector_type(4)));
typedef bf16_t bf16x2 __attribute__((ext_vector_type(2)));
typedef float f32x4_t __attribute__((ext_vector_type(4)));

// ---------------------------------------------------------------- CSR build
__global__ void hist_k(const int* __restrict__ dst, int* __restrict__ cnt, int e) {
    int i = blockIdx.x * blockDim.x + threadIdx.x;
    if (i < e) atomicAdd(&cnt[dst[i]], 1);
}

__global__ void scan_partial_k(const int* __restrict__ cnt, int* __restrict__ part, int n) {
    __shared__ int lds[256];
    int base = blockIdx.x * 1024;
    int t = threadIdx.x;
    int s = 0;
    for (int j = 0; j < 4; j++) {
        int idx = base + t * 4 + j;
        if (idx < n) s += cnt[idx];
    }
    lds[t] = s;
    __syncthreads();
    for (int off = 128; off > 0; off >>= 1) {
        if (t < off) lds[t] += lds[t + off];
        __syncthreads();
    }
    if (t == 0) part[blockIdx.x] = lds[0];
}

__global__ void scan_root_k(int* part, int nb) {
    if (threadIdx.x == 0 && blockIdx.x == 0) {
        int run = 0;
        for (int i = 0; i < nb; i++) { int v = part[i]; part[i] = run; run += v; }
    }
}

__global__ void scan_final_k(const int* __restrict__ cnt, const int* __restrict__ part,
                             int* __restrict__ row_ptr, int* __restrict__ pos, int n) {
    __shared__ int lds[256];
    int base = blockIdx.x * 1024;
    int t = threadIdx.x;
    int v[4];
    int s = 0;
    for (int j = 0; j < 4; j++) {
        int idx = base + t * 4 + j;
        v[j] = (idx < n) ? cnt[idx] : 0;
        s += v[j];
    }
    lds[t] = s;
    __syncthreads();
    for (int off = 1; off < 256; off <<= 1) {
        int xv = (t >= off) ? lds[t - off] : 0;
        __syncthreads();
        lds[t] += xv;
        __syncthreads();
    }
    int ex = (t > 0 ? lds[t - 1] : 0) + part[blockIdx.x];
    for (int j = 0; j < 4; j++) {
        int idx = base + t * 4 + j;
        if (idx < n) {
            row_ptr[idx] = ex;
            pos[idx] = ex;
            if (idx == n - 1) row_ptr[n] = ex + v[j];
            ex += v[j];
        }
    }
}

__global__ void fill_k(const int* __restrict__ src, const int* __restrict__ dst,
                       int* __restrict__ pos, int* __restrict__ col, int e) {
    int i = blockIdx.x * blockDim.x + threadIdx.x;
    if (i < e) {
        int d = dst[i];
        int p = atomicAdd(&pos[d], 1);
        col[p] = src[i];
    }
}

// -------------------------------------------------------------- converters
struct ConvDesc { const float* w; bf16_t* o; int kin; int kpad; };
struct ConvArgs { ConvDesc d[8]; };

// transpose fp32 W[kin][128] -> bf16 WT[128][kpad] (zero-padded K)
__global__ void conv_w_k(ConvArgs args) {
    ConvDesc d = args.d[blockIdx.y];
    int i = blockIdx.x * 256 + threadIdx.x;
    int tot = 128 * d.kpad;
    if (i >= tot) return;
    int n = i / d.kpad, k = i - n * d.kpad;
    float v = (k < d.kin) ? d.w[(size_t)k * 128 + n] : 0.f;
    d.o[i] = (bf16_t)v;
}

// x fp32 [N][50] -> bf16 [N][64] zero-padded
__global__ void conv_x_k(const float* __restrict__ x, bf16_t* __restrict__ xb, int n) {
    int i = blockIdx.x * 256 + threadIdx.x;
    if (i >= n * 64) return;
    int node = i >> 6, k = i & 63;
    xb[i] = (k < D_IN) ? (bf16_t)x[node * D_IN + k] : (bf16_t)0.f;
}

// ------------------------------------------------------------- aggregation
// one wave per node; mean over in-neighbors (bf16 in/out)
__global__ void agg_bf64_k(const bf16_t* __restrict__ feat, const int* __restrict__ rp,
                           const int* __restrict__ col, bf16_t* __restrict__ mean, int n) {
    int wid = (blockIdx.x * blockDim.x + threadIdx.x) >> 6;
    int lane = threadIdx.x & 63;
    if (wid >= n) return;
    int start = rp[wid], end = rp[wid + 1];
    float acc = 0.f;
    int e = start;
    for (; e + 1 < end; e += 2) {
        int s0 = col[e], s1 = col[e + 1];
        acc += (float)feat[(size_t)s0 * 64 + lane];
        acc += (float)feat[(size_t)s1 * 64 + lane];
    }
    if (e < end) acc += (float)feat[(size_t)col[e] * 64 + lane];
    int c = end - start;
    float invc = 1.f / (float)(c > 0 ? c : 1);
    mean[(size_t)wid * 64 + lane] = (bf16_t)(acc * invc);
}

__global__ void agg_bf128_k(const bf16_t* __restrict__ feat, const int* __restrict__ rp,
                            const int* __restrict__ col, bf16_t* __restrict__ mean, int n) {
    int wid = (blockIdx.x * blockDim.x + threadIdx.x) >> 6;
    int lane = threadIdx.x & 63;
    if (wid >= n) return;
    int start = rp[wid], end = rp[wid + 1];
    float ax = 0.f, ay = 0.f;
    int e = start;
    for (; e + 1 < end; e += 2) {
        int s0 = col[e], s1 = col[e + 1];
        bf16x2 v0 = *(const bf16x2*)(feat + (size_t)s0 * 128 + lane * 2);
        bf16x2 v1 = *(const bf16x2*)(feat + (size_t)s1 * 128 + lane * 2);
        ax += (float)v0.x + (float)v1.x;
        ay += (float)v0.y + (float)v1.y;
    }
    if (e < end) {
        bf16x2 v0 = *(const bf16x2*)(feat + (size_t)col[e] * 128 + lane * 2);
        ax += (float)v0.x;
        ay += (float)v0.y;
    }
    int c = end - start;
    float invc = 1.f / (float)(c > 0 ? c : 1);
    bf16x2 o;
    o.x = (bf16_t)(ax * invc);
    o.y = (bf16_t)(ay * invc);
    *(bf16x2*)(mean + (size_t)wid * 128 + lane * 2) = o;
}

// ------------------------------------------------- fused SAGE linear (MFMA)
// out[M][128] = A@W^T_l (+ B@W^T_r) + bias ; optional LN sum/sumsq atomics.
// A,B: bf16 [M][KPAD] row-major (K contiguous). WT: bf16 [128][KPAD] (n-major).
// One wave per 16 rows; fragments loaded straight from global (no LDS).
// A-frag layout: m=lane&15, k=quad*8+j (verified m120); B-frag symmetric.
template <int KPAD, bool DUAL, bool ACC>
__global__ __launch_bounds__(256) void mfma_gemm_k(
    const bf16_t* __restrict__ A, const bf16_t* __restrict__ B,
    const bf16_t* __restrict__ WlT, const bf16_t* __restrict__ WrT,
    const float* __restrict__ bias,
    float* __restrict__ out, double* __restrict__ lnacc, int M) {
    constexpr int KC = KPAD / 32;
    int wave = (blockIdx.x * blockDim.x + threadIdx.x) >> 6;
    int lane = threadIdx.x & 63;
    int row0 = wave * 16;
    if (row0 >= M) return;
    int m = lane & 15;
    int quad = lane >> 4;

    bf16x8 afrag[KC], bfrag[DUAL ? KC : 1];
    {
        const bf16_t* ar = A + (size_t)(row0 + m) * KPAD + quad * 8;
#pragma unroll
        for (int c = 0; c < KC; c++) afrag[c] = *(const bf16x8*)(ar + c * 32);
        if (DUAL) {
            const bf16_t* br = B + (size_t)(row0 + m) * KPAD + quad * 8;
#pragma unroll
            for (int c = 0; c < KC; c++) bfrag[c] = *(const bf16x8*)(br + c * 32);
        }
    }

    float lsum = 0.f, lsum2 = 0.f;
    const int orow = row0 + quad * 4;
#pragma unroll
    for (int nt = 0; nt < 8; nt++) {
        f32x4_t acc = {0.f, 0.f, 0.f, 0.f};
        const bf16_t* wl = WlT + (size_t)(nt * 16 + m) * KPAD + quad * 8;
#pragma unroll
        for (int c = 0; c < KC; c++) {
            bf16x8 wf = *(const bf16x8*)(wl + c * 32);
            acc = __builtin_amdgcn_mfma_f32_16x16x32_bf16(afrag[c], wf, acc, 0, 0, 0);
        }
        if (DUAL) {
            const bf16_t* wr = WrT + (size_t)(nt * 16 + m) * KPAD + quad * 8;
#pragma unroll
            for (int c = 0; c < KC; c++) {
                bf16x8 wf = *(const bf16x8*)(wr + c * 32);
                acc = __builtin_amdgcn_mfma_f32_16x16x32_bf16(bfrag[c], wf, acc, 0, 0, 0);
            }
        }
        float bv = bias ? bias[nt * 16 + m] : 0.f;
#pragma unroll
        for (int r = 0; r < 4; r++) {
            float o = acc[r] + bv;
            out[(size_t)(orow + r) * 128 + nt * 16 + m] = o;
            if (ACC) { lsum += o; lsum2 += o * o; }
        }
    }
    if (ACC) {
        for (int off = 32; off > 0; off >>= 1) {
            lsum += __shfl_down(lsum, off);
            lsum2 += __shfl_down(lsum2, off);
        }
        if (lane == 0) {
            atomicAdd(lnacc, (double)lsum);
            atomicAdd(lnacc + 1, (double)lsum2);
        }
    }
}

// --------------------------------------------- LN (graph mode) + PReLU (+skip)
// MODE 1: out0(bf16) = h1 = prelu(ln(pre)); out1(bf16) = h1 + s
// MODE 2: out0(bf16) = h1in + prelu(ln(pre)) + s
// MODE 3: out0(fp32) = prelu(ln(pre))
template <int MODE>
__global__ void ln_prelu_k(const float* __restrict__ pre, const bf16_t* __restrict__ h1in,
                           const float* __restrict__ s,
                           const float* __restrict__ lnw, const float* __restrict__ lnb,
                           const float* __restrict__ a_ptr, const double* __restrict__ acc,
                           void* __restrict__ out0v, void* __restrict__ out1v, int total) {
    int i = blockIdx.x * blockDim.x + threadIdx.x;  // float4 index
    if (i * 4 >= total) return;
    double cinv = 1.0 / (double)total;
    double mm = acc[0] * cinv;
    double var = acc[1] * cinv - mm * mm;
    float stdv = (float)sqrt(var > 0.0 ? var : 0.0);
    float scale = 1.0f / (stdv + LN_EPS);
    float mf = (float)mm;
    float a = a_ptr[0];
    int c4 = i & 31;
    float4 w = ((const float4*)lnw)[c4];
    float4 b = ((const float4*)lnb)[c4];
    float4 p = ((const float4*)pre)[i];
    float4 h;
    h.x = (p.x - mf) * scale * w.x + b.x;
    h.y = (p.y - mf) * scale * w.y + b.y;
    h.z = (p.z - mf) * scale * w.z + b.z;
    h.w = (p.w - mf) * scale * w.w + b.w;
    h.x = h.x >= 0.f ? h.x : a * h.x;
    h.y = h.y >= 0.f ? h.y : a * h.y;
    h.z = h.z >= 0.f ? h.z : a * h.z;
    h.w = h.w >= 0.f ? h.w : a * h.w;
    if (MODE == 1) {
        bf16x4 hb;
        hb.x = (bf16_t)h.x; hb.y = (bf16_t)h.y; hb.z = (bf16_t)h.z; hb.w = (bf16_t)h.w;
        ((bf16x4*)out0v)[i] = hb;
        float4 sv = ((const float4*)s)[i];
        bf16x4 tb;
        tb.x = (bf16_t)(h.x + sv.x); tb.y = (bf16_t)(h.y + sv.y);
        tb.z = (bf16_t)(h.z + sv.z); tb.w = (bf16_t)(h.w + sv.w);
        ((bf16x4*)out1v)[i] = tb;
    } else if (MODE == 2) {
        bf16x4 hv = ((const bf16x4*)h1in)[i];
        float4 sv = ((const float4*)s)[i];
        bf16x4 tb;
        tb.x = (bf16_t)((float)hv.x + h.x + sv.x);
        tb.y = (bf16_t)((float)hv.y + h.y + sv.y);
        tb.z = (bf16_t)((float)hv.z + h.z + sv.z);
        tb.w = (bf16_t)((float)hv.w + h.w + sv.w);
        ((bf16x4*)out0v)[i] = tb;
    } else {
        ((float4*)out0v)[i] = h;
    }
}

// ------------------------------------------------------------------ launch
extern "C" void kernel_launch(void* const* d_in, const int* in_sizes, int n_in,
                              void* d_out, int out_size, void* d_ws, size_t ws_size,
                              hipStream_t stream) {
    const float* x    = (const float*)d_in[0];
    const int*   esrc = (const int*)d_in[1];
    const int*   edst = (const int*)d_in[2];
    const float* Wl1  = (const float*)d_in[3];
    const float* Wr1  = (const float*)d_in[4];
    const float* b1   = (const float*)d_in[5];
    const float* Wl2  = (const float*)d_in[6];
    const float* Wr2  = (const float*)d_in[7];
    const float* b2   = (const float*)d_in[8];
    const float* Wl3  = (const float*)d_in[9];
    const float* Wr3  = (const float*)d_in[10];
    const float* b3   = (const float*)d_in[11];
    const float* Ws1  = (const float*)d_in[12];
    const float* Ws2  = (const float*)d_in[13];
    const float* lnw1 = (const float*)d_in[14];
    const float* lnb1 = (const float*)d_in[15];
    const float* lnw2 = (const float*)d_in[16];
    const float* lnb2 = (const float*)d_in[17];
    const float* lnw3 = (const float*)d_in[18];
    const float* lnb3 = (const float*)d_in[19];
    const float* a1   = (const float*)d_in[20];
    const float* a2   = (const float*)d_in[21];
    const float* a3   = (const float*)d_in[22];

    const int N = in_sizes[0] / D_IN;
    const int E = in_sizes[1];

    char* ws = (char*)d_ws;
    size_t off = 0;
    auto alloc = [&](size_t bytes) -> void* {
        void* p = ws + off;
        off += (bytes + 255) & ~(size_t)255;
        return p;
    };
    bf16_t* xb   = (bf16_t*)alloc((size_t)N * 64 * 2);    // x padded bf16
    bf16_t* mean = (bf16_t*)alloc((size_t)N * 128 * 2);   // agg mean (layer1 uses [N][64])
    float*  PRE  = (float*)alloc((size_t)N * 128 * 4);    // GEMM out / LN in
    float*  C    = (float*)alloc((size_t)N * 128 * 4);    // skip (x@Ws)
    bf16_t* h1b  = (bf16_t*)alloc((size_t)N * 128 * 2);   // h1
    bf16_t* TB   = (bf16_t*)alloc((size_t)N * 128 * 2);   // t2 then t3
    bf16_t* WT   = (bf16_t*)alloc((size_t)(4 * 128 * 64 + 4 * 128 * 128) * 2);
    int* cnt  = (int*)alloc((size_t)N * 4);
    int* rp   = (int*)alloc((size_t)(N + 1) * 4);
    int* pos  = (int*)alloc((size_t)N * 4);
    int* col  = (int*)alloc((size_t)E * 4);
    int* part = (int*)alloc(512);
    double* lnacc = (double*)alloc(6 * 8);

    bf16_t* Wl1T = WT;                  // [128][64]
    bf16_t* Wr1T = Wl1T + 128 * 64;
    bf16_t* Ws1T = Wr1T + 128 * 64;
    bf16_t* Ws2T = Ws1T + 128 * 64;
    bf16_t* Wl2T = Ws2T + 128 * 64;     // [128][128]
    bf16_t* Wr2T = Wl2T + 128 * 128;
    bf16_t* Wl3T = Wr2T + 128 * 128;
    bf16_t* Wr3T = Wl3T + 128 * 128;

    hipMemsetAsync(cnt, 0, (size_t)N * 4, stream);
    hipMemsetAsync(lnacc, 0, 48, stream);

    // CSR
    const int CH = 1024;
    const int NBS = (N + CH - 1) / CH;
    hist_k<<<(E + 255) / 256, 256, 0, stream>>>(edst, cnt, E);
    scan_partial_k<<<NBS, 256, 0, stream>>>(cnt, part, N);
    scan_root_k<<<1, 64, 0, stream>>>(part, NBS);
    scan_final_k<<<NBS, 256, 0, stream>>>(cnt, part, rp, pos, N);
    fill_k<<<(E + 255) / 256, 256, 0, stream>>>(esrc, edst, pos, col, E);

    // weight/feature conversion
    ConvArgs ca;
    ca.d[0] = {Wl1, Wl1T, 50, 64};
    ca.d[1] = {Wr1, Wr1T, 50, 64};
    ca.d[2] = {Ws1, Ws1T, 50, 64};
    ca.d[3] = {Ws2, Ws2T, 50, 64};
    ca.d[4] = {Wl2, Wl2T, 128, 128};
    ca.d[5] = {Wr2, Wr2T, 128, 128};
    ca.d[6] = {Wl3, Wl3T, 128, 128};
    ca.d[7] = {Wr3, Wr3T, 128, 128};
    conv_w_k<<<dim3(64, 8), 256, 0, stream>>>(ca);
    conv_x_k<<<(N * 64 + 255) / 256, 256, 0, stream>>>(x, xb, N);

    const int aggBlocks = ((N * 64) + 255) / 256;
    const int gemmBlocks = (N + 63) / 64;
    const int lnBlocks = (N * 128 / 4 + 255) / 256;
    const int total = N * 128;

    // ---- layer 1
    agg_bf64_k<<<aggBlocks, 256, 0, stream>>>(xb, rp, col, mean, N);
    mfma_gemm_k<64, true, true><<<gemmBlocks, 256, 0, stream>>>(
        mean, xb, Wl1T, Wr1T, b1, PRE, lnacc + 0, N);
    mfma_gemm_k<64, false, false><<<gemmBlocks, 256, 0, stream>>>(
        xb, nullptr, Ws1T, nullptr, nullptr, C, nullptr, N);
    ln_prelu_k<1><<<lnBlocks, 256, 0, stream>>>(
        PRE, nullptr, C, lnw1, lnb1, a1, lnacc + 0, h1b, TB, total);  // h1b, t2

    // ---- layer 2
    agg_bf128_k<<<aggBlocks, 256, 0, stream>>>(TB, rp, col, mean, N);
    mfma_gemm_k<64, false, false><<<gemmBlocks, 256, 0, stream>>>(
        xb, nullptr, Ws2T, nullptr, nullptr, C, nullptr, N);
    mfma_gemm_k<128, true, true><<<gemmBlocks, 256, 0, stream>>>(
        mean, TB, Wl2T, Wr2T, b2, PRE, lnacc + 2, N);
    ln_prelu_k<2><<<lnBlocks, 256, 0, stream>>>(
        PRE, h1b, C, lnw2, lnb2, a2, lnacc + 2, TB, nullptr, total);  // t3

    // ---- layer 3
    agg_bf128_k<<<aggBlocks, 256, 0, stream>>>(TB, rp, col, mean, N);
    mfma_gemm_k<128, true, true><<<gemmBlocks, 256, 0, stream>>>(
        mean, TB, Wl3T, Wr3T, b3, PRE, lnacc + 4, N);
    ln_prelu_k<3><<<lnBlocks, 256, 0, stream>>>(
        PRE, nullptr, nullptr, lnw3, lnb3, a3, lnacc + 4, d_out, nullptr, total);
}

// Round 3
// 738.163 us; speedup vs baseline: 2.1805x; 1.6890x over previous
//
#include <hip/hip_runtime.h>

#define D_IN 50
#define LN_EPS 1e-5f

typedef __bf16 bf16_t;
typedef bf16_t bf16x8 __attribute__((ext_vector_type(8)));
typedef bf16_t bf16x4 __attribute__((ext_vector_type(4)));
typedef bf16_t bf16x2 __attribute__((ext_vector_type(2)));
typedef float f32x4_t __attribute__((ext_vector_type(4)));

// ---------------------------------------------------------------- CSR build
__global__ void hist_k(const int* __restrict__ dst, int* __restrict__ cnt, int e) {
    int i = blockIdx.x * blockDim.x + threadIdx.x;
    if (i < e) atomicAdd(&cnt[dst[i]], 1);
}

__global__ void scan_partial_k(const int* __restrict__ cnt, int* __restrict__ part, int n) {
    __shared__ int lds[256];
    int base = blockIdx.x * 1024;
    int t = threadIdx.x;
    int s = 0;
    for (int j = 0; j < 4; j++) {
        int idx = base + t * 4 + j;
        if (idx < n) s += cnt[idx];
    }
    lds[t] = s;
    __syncthreads();
    for (int off = 128; off > 0; off >>= 1) {
        if (t < off) lds[t] += lds[t + off];
        __syncthreads();
    }
    if (t == 0) part[blockIdx.x] = lds[0];
}

__global__ void scan_root_k(int* part, int nb) {
    if (threadIdx.x == 0 && blockIdx.x == 0) {
        int run = 0;
        for (int i = 0; i < nb; i++) { int v = part[i]; part[i] = run; run += v; }
    }
}

__global__ void scan_final_k(const int* __restrict__ cnt, const int* __restrict__ part,
                             int* __restrict__ row_ptr, int* __restrict__ pos, int n) {
    __shared__ int lds[256];
    int base = blockIdx.x * 1024;
    int t = threadIdx.x;
    int v[4];
    int s = 0;
    for (int j = 0; j < 4; j++) {
        int idx = base + t * 4 + j;
        v[j] = (idx < n) ? cnt[idx] : 0;
        s += v[j];
    }
    lds[t] = s;
    __syncthreads();
    for (int off = 1; off < 256; off <<= 1) {
        int xv = (t >= off) ? lds[t - off] : 0;
        __syncthreads();
        lds[t] += xv;
        __syncthreads();
    }
    int ex = (t > 0 ? lds[t - 1] : 0) + part[blockIdx.x];
    for (int j = 0; j < 4; j++) {
        int idx = base + t * 4 + j;
        if (idx < n) {
            row_ptr[idx] = ex;
            pos[idx] = ex;
            if (idx == n - 1) row_ptr[n] = ex + v[j];
            ex += v[j];
        }
    }
}

__global__ void fill_k(const int* __restrict__ src, const int* __restrict__ dst,
                       int* __restrict__ pos, int* __restrict__ col, int e) {
    int i = blockIdx.x * blockDim.x + threadIdx.x;
    if (i < e) {
        int d = dst[i];
        int p = atomicAdd(&pos[d], 1);
        col[p] = src[i];
    }
}

// -------------------------------------------------------------- converters
struct ConvDesc { const float* w; bf16_t* o; int kin; int kpad; };
struct ConvArgs { ConvDesc d[8]; };

__global__ void conv_w_k(ConvArgs args) {
    ConvDesc d = args.d[blockIdx.y];
    int i = blockIdx.x * 256 + threadIdx.x;
    int tot = 128 * d.kpad;
    if (i >= tot) return;
    int n = i / d.kpad, k = i - n * d.kpad;
    float v = (k < d.kin) ? d.w[(size_t)k * 128 + n] : 0.f;
    d.o[i] = (bf16_t)v;
}

__global__ void conv_x_k(const float* __restrict__ x, bf16_t* __restrict__ xb, int n) {
    int i = blockIdx.x * 256 + threadIdx.x;
    if (i >= n * 64) return;
    int node = i >> 6, k = i & 63;
    xb[i] = (k < D_IN) ? (bf16_t)x[node * D_IN + k] : (bf16_t)0.f;
}

// ------------------------------------------------------------- aggregation
__global__ void agg_bf64_k(const bf16_t* __restrict__ feat, const int* __restrict__ rp,
                           const int* __restrict__ col, bf16_t* __restrict__ mean, int n) {
    int wid = (blockIdx.x * blockDim.x + threadIdx.x) >> 6;
    int lane = threadIdx.x & 63;
    if (wid >= n) return;
    int start = rp[wid], end = rp[wid + 1];
    float a0 = 0.f, a1 = 0.f;
    int e = start;
    for (; e + 3 < end; e += 4) {
        int s0 = col[e], s1 = col[e + 1], s2 = col[e + 2], s3 = col[e + 3];
        float v0 = (float)feat[(size_t)s0 * 64 + lane];
        float v1 = (float)feat[(size_t)s1 * 64 + lane];
        float v2 = (float)feat[(size_t)s2 * 64 + lane];
        float v3 = (float)feat[(size_t)s3 * 64 + lane];
        a0 += v0 + v1;
        a1 += v2 + v3;
    }
    for (; e < end; e++) a0 += (float)feat[(size_t)col[e] * 64 + lane];
    int c = end - start;
    float invc = 1.f / (float)(c > 0 ? c : 1);
    mean[(size_t)wid * 64 + lane] = (bf16_t)((a0 + a1) * invc);
}

__global__ void agg_bf128_k(const bf16_t* __restrict__ feat, const int* __restrict__ rp,
                            const int* __restrict__ col, bf16_t* __restrict__ mean, int n) {
    int wid = (blockIdx.x * blockDim.x + threadIdx.x) >> 6;
    int lane = threadIdx.x & 63;
    if (wid >= n) return;
    int start = rp[wid], end = rp[wid + 1];
    float ax0 = 0.f, ay0 = 0.f, ax1 = 0.f, ay1 = 0.f;
    int e = start;
    for (; e + 3 < end; e += 4) {
        int s0 = col[e], s1 = col[e + 1], s2 = col[e + 2], s3 = col[e + 3];
        bf16x2 v0 = *(const bf16x2*)(feat + (size_t)s0 * 128 + lane * 2);
        bf16x2 v1 = *(const bf16x2*)(feat + (size_t)s1 * 128 + lane * 2);
        bf16x2 v2 = *(const bf16x2*)(feat + (size_t)s2 * 128 + lane * 2);
        bf16x2 v3 = *(const bf16x2*)(feat + (size_t)s3 * 128 + lane * 2);
        ax0 += (float)v0.x + (float)v1.x;
        ay0 += (float)v0.y + (float)v1.y;
        ax1 += (float)v2.x + (float)v3.x;
        ay1 += (float)v2.y + (float)v3.y;
    }
    for (; e < end; e++) {
        bf16x2 v0 = *(const bf16x2*)(feat + (size_t)col[e] * 128 + lane * 2);
        ax0 += (float)v0.x;
        ay0 += (float)v0.y;
    }
    int c = end - start;
    float invc = 1.f / (float)(c > 0 ? c : 1);
    bf16x2 o;
    o.x = (bf16_t)((ax0 + ax1) * invc);
    o.y = (bf16_t)((ay0 + ay1) * invc);
    *(bf16x2*)(mean + (size_t)wid * 128 + lane * 2) = o;
}

// ------------------------------------------------- fused SAGE linear (MFMA)
// out[M][128] = A@WlT^T (+ B@WrT^T) + bias. Weights staged to LDS once per
// block, pre-swizzled into fragment order so main-loop ds_read is lane*16
// linear (conflict-free). One wave = 32 rows (2 subtiles share each weight
// fragment). LN partials: one float2 per wave slot (no contested atomics).
template <int KPAD, bool DUAL, bool ACC>
__global__ __launch_bounds__(256) void mfma_gemm_k(
    const bf16_t* __restrict__ A, const bf16_t* __restrict__ B,
    const bf16_t* __restrict__ WlT, const bf16_t* __restrict__ WrT,
    const float* __restrict__ bias,
    float* __restrict__ out, float2* __restrict__ partials, int M) {
    constexpr int KC = KPAD / 32;
    constexpr int WELE = 8 * KC * 64 * 8;  // bf16 elements per weight in LDS
    __shared__ bf16_t lwl[WELE];
    __shared__ bf16_t lwr[DUAL ? WELE : 8];

    const int tid = threadIdx.x;
    // stage weights, swizzled: chunk ch -> (nt, c, lane); LDS addr = ch*16B
    for (int ch = tid; ch < 8 * KC * 64; ch += 256) {
        int nt = ch / (KC * 64);
        int rem = ch - nt * (KC * 64);
        int c = rem >> 6;
        int ln = rem & 63;
        int m = ln & 15, q = ln >> 4;
        size_t srcoff = (size_t)(nt * 16 + m) * KPAD + c * 32 + q * 8;
        *(bf16x8*)&lwl[ch * 8] = *(const bf16x8*)(WlT + srcoff);
        if (DUAL) *(bf16x8*)&lwr[ch * 8] = *(const bf16x8*)(WrT + srcoff);
    }
    __syncthreads();

    const int wid = blockIdx.x * 4 + (tid >> 6);
    const int lane = tid & 63;
    const int row0 = wid * 32;
    if (row0 >= M) return;
    const int m = lane & 15;
    const int q = lane >> 4;

    bf16x8 af[2][KC], bfr[DUAL ? 2 : 1][DUAL ? KC : 1];
#pragma unroll
    for (int s = 0; s < 2; s++) {
        const bf16_t* ar = A + (size_t)(row0 + s * 16 + m) * KPAD + q * 8;
#pragma unroll
        for (int c = 0; c < KC; c++) af[s][c] = *(const bf16x8*)(ar + c * 32);
        if (DUAL) {
            const bf16_t* br = B + (size_t)(row0 + s * 16 + m) * KPAD + q * 8;
#pragma unroll
            for (int c = 0; c < KC; c++) bfr[s][c] = *(const bf16x8*)(br + c * 32);
        }
    }

    float lsum = 0.f, lsum2 = 0.f;
#pragma unroll
    for (int nt = 0; nt < 8; nt++) {
        f32x4_t acc0 = {0.f, 0.f, 0.f, 0.f};
        f32x4_t acc1 = {0.f, 0.f, 0.f, 0.f};
#pragma unroll
        for (int c = 0; c < KC; c++) {
            bf16x8 w = *(const bf16x8*)&lwl[((nt * KC + c) * 64 + lane) * 8];
            acc0 = __builtin_amdgcn_mfma_f32_16x16x32_bf16(af[0][c], w, acc0, 0, 0, 0);
            acc1 = __builtin_amdgcn_mfma_f32_16x16x32_bf16(af[1][c], w, acc1, 0, 0, 0);
        }
        if (DUAL) {
#pragma unroll
            for (int c = 0; c < KC; c++) {
                bf16x8 w = *(const bf16x8*)&lwr[((nt * KC + c) * 64 + lane) * 8];
                acc0 = __builtin_amdgcn_mfma_f32_16x16x32_bf16(bfr[0][c], w, acc0, 0, 0, 0);
                acc1 = __builtin_amdgcn_mfma_f32_16x16x32_bf16(bfr[1][c], w, acc1, 0, 0, 0);
            }
        }
        float bv = bias ? bias[nt * 16 + m] : 0.f;
#pragma unroll
        for (int s = 0; s < 2; s++) {
            f32x4_t* ap = (s == 0) ? &acc0 : &acc1;
#pragma unroll
            for (int r = 0; r < 4; r++) {
                int row = row0 + s * 16 + q * 4 + r;
                if (row < M) {
                    float o = (*ap)[r] + bv;
                    out[(size_t)row * 128 + nt * 16 + m] = o;
                    if (ACC) { lsum += o; lsum2 += o * o; }
                }
            }
        }
    }
    if (ACC) {
        for (int off = 32; off > 0; off >>= 1) {
            lsum += __shfl_down(lsum, off);
            lsum2 += __shfl_down(lsum2, off);
        }
        if (lane == 0) partials[wid] = make_float2(lsum, lsum2);
    }
}

// sum per-wave partials -> lnacc[0], lnacc[1] (double)
__global__ void reduce_partials_k(const float2* __restrict__ p, int n,
                                  double* __restrict__ outp) {
    __shared__ double s1[256], s2[256];
    int t = threadIdx.x;
    double a = 0.0, b = 0.0;
    for (int i = t; i < n; i += 256) { a += (double)p[i].x; b += (double)p[i].y; }
    s1[t] = a; s2[t] = b;
    __syncthreads();
    for (int off = 128; off > 0; off >>= 1) {
        if (t < off) { s1[t] += s1[t + off]; s2[t] += s2[t + off]; }
        __syncthreads();
    }
    if (t == 0) { outp[0] = s1[0]; outp[1] = s2[0]; }
}

// --------------------------------------------- LN (graph mode) + PReLU (+skip)
template <int MODE>
__global__ void ln_prelu_k(const float* __restrict__ pre, const bf16_t* __restrict__ h1in,
                           const float* __restrict__ s,
                           const float* __restrict__ lnw, const float* __restrict__ lnb,
                           const float* __restrict__ a_ptr, const double* __restrict__ acc,
                           void* __restrict__ out0v, void* __restrict__ out1v, int total) {
    int i = blockIdx.x * blockDim.x + threadIdx.x;
    if (i * 4 >= total) return;
    double cinv = 1.0 / (double)total;
    double mm = acc[0] * cinv;
    double var = acc[1] * cinv - mm * mm;
    float stdv = (float)sqrt(var > 0.0 ? var : 0.0);
    float scale = 1.0f / (stdv + LN_EPS);
    float mf = (float)mm;
    float a = a_ptr[0];
    int c4 = i & 31;
    float4 w = ((const float4*)lnw)[c4];
    float4 b = ((const float4*)lnb)[c4];
    float4 p = ((const float4*)pre)[i];
    float4 h;
    h.x = (p.x - mf) * scale * w.x + b.x;
    h.y = (p.y - mf) * scale * w.y + b.y;
    h.z = (p.z - mf) * scale * w.z + b.z;
    h.w = (p.w - mf) * scale * w.w + b.w;
    h.x = h.x >= 0.f ? h.x : a * h.x;
    h.y = h.y >= 0.f ? h.y : a * h.y;
    h.z = h.z >= 0.f ? h.z : a * h.z;
    h.w = h.w >= 0.f ? h.w : a * h.w;
    if (MODE == 1) {
        bf16x4 hb;
        hb.x = (bf16_t)h.x; hb.y = (bf16_t)h.y; hb.z = (bf16_t)h.z; hb.w = (bf16_t)h.w;
        ((bf16x4*)out0v)[i] = hb;
        float4 sv = ((const float4*)s)[i];
        bf16x4 tb;
        tb.x = (bf16_t)(h.x + sv.x); tb.y = (bf16_t)(h.y + sv.y);
        tb.z = (bf16_t)(h.z + sv.z); tb.w = (bf16_t)(h.w + sv.w);
        ((bf16x4*)out1v)[i] = tb;
    } else if (MODE == 2) {
        bf16x4 hv = ((const bf16x4*)h1in)[i];
        float4 sv = ((const float4*)s)[i];
        bf16x4 tb;
        tb.x = (bf16_t)((float)hv.x + h.x + sv.x);
        tb.y = (bf16_t)((float)hv.y + h.y + sv.y);
        tb.z = (bf16_t)((float)hv.z + h.z + sv.z);
        tb.w = (bf16_t)((float)hv.w + h.w + sv.w);
        ((bf16x4*)out0v)[i] = tb;
    } else {
        ((float4*)out0v)[i] = h;
    }
}

// ------------------------------------------------------------------ launch
extern "C" void kernel_launch(void* const* d_in, const int* in_sizes, int n_in,
                              void* d_out, int out_size, void* d_ws, size_t ws_size,
                              hipStream_t stream) {
    const float* x    = (const float*)d_in[0];
    const int*   esrc = (const int*)d_in[1];
    const int*   edst = (const int*)d_in[2];
    const float* Wl1  = (const float*)d_in[3];
    const float* Wr1  = (const float*)d_in[4];
    const float* b1   = (const float*)d_in[5];
    const float* Wl2  = (const float*)d_in[6];
    const float* Wr2  = (const float*)d_in[7];
    const float* b2   = (const float*)d_in[8];
    const float* Wl3  = (const float*)d_in[9];
    const float* Wr3  = (const float*)d_in[10];
    const float* b3   = (const float*)d_in[11];
    const float* Ws1  = (const float*)d_in[12];
    const float* Ws2  = (const float*)d_in[13];
    const float* lnw1 = (const float*)d_in[14];
    const float* lnb1 = (const float*)d_in[15];
    const float* lnw2 = (const float*)d_in[16];
    const float* lnb2 = (const float*)d_in[17];
    const float* lnw3 = (const float*)d_in[18];
    const float* lnb3 = (const float*)d_in[19];
    const float* a1   = (const float*)d_in[20];
    const float* a2   = (const float*)d_in[21];
    const float* a3   = (const float*)d_in[22];

    const int N = in_sizes[0] / D_IN;
    const int E = in_sizes[1];

    char* ws = (char*)d_ws;
    size_t off = 0;
    auto alloc = [&](size_t bytes) -> void* {
        void* p = ws + off;
        off += (bytes + 255) & ~(size_t)255;
        return p;
    };
    bf16_t* xb   = (bf16_t*)alloc((size_t)N * 64 * 2);
    bf16_t* mean = (bf16_t*)alloc((size_t)N * 128 * 2);
    float*  PRE  = (float*)alloc((size_t)N * 128 * 4);
    float*  C    = (float*)alloc((size_t)N * 128 * 4);
    bf16_t* h1b  = (bf16_t*)alloc((size_t)N * 128 * 2);
    bf16_t* TB   = (bf16_t*)alloc((size_t)N * 128 * 2);
    bf16_t* WT   = (bf16_t*)alloc((size_t)(4 * 128 * 64 + 4 * 128 * 128) * 2);
    int* cnt  = (int*)alloc((size_t)N * 4);
    int* rp   = (int*)alloc((size_t)(N + 1) * 4);
    int* pos  = (int*)alloc((size_t)N * 4);
    int* col  = (int*)alloc((size_t)E * 4);
    int* part = (int*)alloc(512);
    double* lnacc = (double*)alloc(6 * 8);
    const int tiles = (N + 31) / 32;
    float2* partials = (float2*)alloc((size_t)tiles * 8);

    bf16_t* Wl1T = WT;
    bf16_t* Wr1T = Wl1T + 128 * 64;
    bf16_t* Ws1T = Wr1T + 128 * 64;
    bf16_t* Ws2T = Ws1T + 128 * 64;
    bf16_t* Wl2T = Ws2T + 128 * 64;
    bf16_t* Wr2T = Wl2T + 128 * 128;
    bf16_t* Wl3T = Wr2T + 128 * 128;
    bf16_t* Wr3T = Wl3T + 128 * 128;

    hipMemsetAsync(cnt, 0, (size_t)N * 4, stream);

    const int CH = 1024;
    const int NBS = (N + CH - 1) / CH;
    hist_k<<<(E + 255) / 256, 256, 0, stream>>>(edst, cnt, E);
    scan_partial_k<<<NBS, 256, 0, stream>>>(cnt, part, N);
    scan_root_k<<<1, 64, 0, stream>>>(part, NBS);
    scan_final_k<<<NBS, 256, 0, stream>>>(cnt, part, rp, pos, N);
    fill_k<<<(E + 255) / 256, 256, 0, stream>>>(esrc, edst, pos, col, E);

    ConvArgs ca;
    ca.d[0] = {Wl1, Wl1T, 50, 64};
    ca.d[1] = {Wr1, Wr1T, 50, 64};
    ca.d[2] = {Ws1, Ws1T, 50, 64};
    ca.d[3] = {Ws2, Ws2T, 50, 64};
    ca.d[4] = {Wl2, Wl2T, 128, 128};
    ca.d[5] = {Wr2, Wr2T, 128, 128};
    ca.d[6] = {Wl3, Wl3T, 128, 128};
    ca.d[7] = {Wr3, Wr3T, 128, 128};
    conv_w_k<<<dim3(64, 8), 256, 0, stream>>>(ca);
    conv_x_k<<<(N * 64 + 255) / 256, 256, 0, stream>>>(x, xb, N);

    const int aggBlocks = ((N * 64) + 255) / 256;
    const int gemmBlocks = (tiles + 3) / 4;
    const int lnBlocks = (N * 128 / 4 + 255) / 256;
    const int total = N * 128;

    // ---- layer 1
    agg_bf64_k<<<aggBlocks, 256, 0, stream>>>(xb, rp, col, mean, N);
    mfma_gemm_k<64, true, true><<<gemmBlocks, 256, 0, stream>>>(
        mean, xb, Wl1T, Wr1T, b1, PRE, partials, N);
    reduce_partials_k<<<1, 256, 0, stream>>>(partials, tiles, lnacc + 0);
    mfma_gemm_k<64, false, false><<<gemmBlocks, 256, 0, stream>>>(
        xb, nullptr, Ws1T, nullptr, nullptr, C, nullptr, N);
    ln_prelu_k<1><<<lnBlocks, 256, 0, stream>>>(
        PRE, nullptr, C, lnw1, lnb1, a1, lnacc + 0, h1b, TB, total);

    // ---- layer 2
    agg_bf128_k<<<aggBlocks, 256, 0, stream>>>(TB, rp, col, mean, N);
    mfma_gemm_k<64, false, false><<<gemmBlocks, 256, 0, stream>>>(
        xb, nullptr, Ws2T, nullptr, nullptr, C, nullptr, N);
    mfma_gemm_k<128, true, true><<<gemmBlocks, 256, 0, stream>>>(
        mean, TB, Wl2T, Wr2T, b2, PRE, partials, N);
    reduce_partials_k<<<1, 256, 0, stream>>>(partials, tiles, lnacc + 2);
    ln_prelu_k<2><<<lnBlocks, 256, 0, stream>>>(
        PRE, h1b, C, lnw2, lnb2, a2, lnacc + 2, TB, nullptr, total);

    // ---- layer 3
    agg_bf128_k<<<aggBlocks, 256, 0, stream>>>(TB, rp, col, mean, N);
    mfma_gemm_k<128, true, true><<<gemmBlocks, 256, 0, stream>>>(
        mean, TB, Wl3T, Wr3T, b3, PRE, partials, N);
    reduce_partials_k<<<1, 256, 0, stream>>>(partials, tiles, lnacc + 4);
    ln_prelu_k<3><<<lnBlocks, 256, 0, stream>>>(
        PRE, nullptr, nullptr, lnw3, lnb3, a3, lnacc + 4, d_out, nullptr, total);
}